// Round 11
// baseline (10971.420 us; speedup 1.0000x reference)
//
#include <hip/hip_runtime.h>

typedef short short8 __attribute__((ext_vector_type(8)));
typedef float f32x4  __attribute__((ext_vector_type(4)));
typedef unsigned long long u64;

#define NWG 96           // 32 wgs per layer, 16 units each
#define NSTEP 515
#define NGRP 8           // barrier groups
#define GSZ  12          // arrivers per group (96/8)

// ---- workspace layout (bytes) ----
#define OFF_WH1  0ull              // packed Whh1 frags: 32 ug * 64KB = 2MB
#define OFF_WH2  2097152ull        // packed Whh2
#define OFF_WH3  4194304ull        // packed Whh3
#define OFF_WI2  6291456ull        // packed Wih2 (streamed, L2-resident)
#define OFF_WI3  8388608ull        // packed Wih3
#define OFF_V1   10485760ull       // v1[2048] f32 (Wih1 @ W1)
#define OFF_U1   10493952ull       // u1[2048] f32 (Wih1 @ b1 + bih1 + bhh1)
#define OFF_B2   10502144ull       // bias2[2048] f32
#define OFF_B3   10510336ull       // bias3[2048] f32
#define OFF_XT   10518528ull       // xT[512][128] f32 (256KB)
#define OFF_HR   10780672ull       // h rings: [3 layer][2 slot][16 kb][8 mb][512] u16 = 768KB
#define OFF_P3   11567104ull       // part3: [3 slot][32][128] f32 = 48KB (3-ring)
#define OFF_BAR  11616256ull       // barrier block (4KB): main @u32[0..511], abl @u32[512..1023]

__device__ __forceinline__ unsigned short bf16rne(float f) {
    unsigned u = __float_as_uint(f);
    return (unsigned short)((u + 0x7FFFu + ((u >> 16) & 1u)) >> 16);
}

__device__ __forceinline__ float sigm(float x) { return 1.0f / (1.0f + expf(-x)); }

// Coherent (agent-scope, relaxed) 16B fragment load as 2x u64: bypasses stale
// L2 (sc bits); relaxed => no cache-maintenance ops, pipelines like a load.
__device__ __forceinline__ short8 cload(const u64* p) {
    union { u64 d[2]; short8 s; } f;
    f.d[0] = __hip_atomic_load(p,     __ATOMIC_RELAXED, __HIP_MEMORY_SCOPE_AGENT);
    f.d[1] = __hip_atomic_load(p + 1, __ATOMIC_RELAXED, __HIP_MEMORY_SCOPE_AGENT);
    return f.s;
}

// Sentinel: 0.0508 absmax -> nothing ran; ~0.75 -> lstm_main broken; ~2e-4 -> PASS.
__global__ void fill_sentinel(float* __restrict__ out)
{
    int e = blockIdx.x * 256 + threadIdx.x;
    if (e < 65536) out[e] = 0.75f;
}

__global__ void zero_bar(char* __restrict__ ws)
{
    unsigned* b = (unsigned*)(ws + OFF_BAR);
    b[threadIdx.x] = 0u;                   // 1024 thr clear 4KB
}

// Zero h rings + part3 in a PRE-kernel (kernel-boundary flush publishes zeros).
__global__ void zero_hr(char* __restrict__ ws)
{
    int e = blockIdx.x * 256 + threadIdx.x;
    float4 z = {0.f, 0.f, 0.f, 0.f};
    if (e < 52224) *(float4*)(ws + OFF_HR + (size_t)e * 16) = z;  // HR(768K)+P3(48K)
}

// Pack one 2048x512 gate matrix into MFMA B-fragments (bf16 bits).
__global__ void pack_w(const float* __restrict__ W, unsigned short* __restrict__ dst)
{
    int e = blockIdx.x * 256 + threadIdx.x;     // exactly 1,048,576
    int j    = e & 7;
    int lane = (e >> 3) & 63;
    int kb   = (e >> 9) & 15;
    int nb   = (e >> 13) & 3;
    int ug   = e >> 15;
    int row = nb * 512 + ug * 16 + (lane & 15);
    int col = kb * 32 + (lane >> 4) * 8 + j;
    dst[e] = bf16rne(W[row * 512 + col]);
}

// v1 = Wih1 @ W1[:,0]; u1 = Wih1 @ b1 + bih1 + bhh1; bias2/3 = bih+bhh
__global__ void prep_vec(const float* __restrict__ Wih1, const float* __restrict__ W1,
                         const float* __restrict__ b1,
                         const float* __restrict__ bih1, const float* __restrict__ bhh1,
                         const float* __restrict__ bih2, const float* __restrict__ bhh2,
                         const float* __restrict__ bih3, const float* __restrict__ bhh3,
                         float* __restrict__ v1, float* __restrict__ u1,
                         float* __restrict__ bias2, float* __restrict__ bias3)
{
    int r = blockIdx.x * 256 + threadIdx.x;
    if (r >= 2048) return;
    float sv = 0.f, su = 0.f;
    for (int k = 0; k < 512; ++k) {
        float w = Wih1[r * 512 + k];
        sv += w * W1[k];
        su += w * b1[k];
    }
    v1[r] = sv;
    u1[r] = su + bih1[r] + bhh1[r];
    bias2[r] = bih2[r] + bhh2[r];
    bias3[r] = bih3[r] + bhh3[r];
}

__global__ void prep_xt(const float* __restrict__ x, float* __restrict__ xT)
{
    int e = blockIdx.x * 256 + threadIdx.x;
    if (e >= 65536) return;
    int b = e >> 9, t = e & 511;
    xT[t * 128 + b] = x[e];
}

// ---- fence-free hierarchical split-phase barrier (as R10) ----
__device__ __forceinline__ void gbar_arrive(unsigned* bar, int wg, unsigned s)
{
    __syncthreads();                      // drains vmcnt: h stores at coherence pt
    if (threadIdx.x == 0) {
        unsigned g = (unsigned)wg & 7u;
        unsigned old = atomicAdd(bar + 64 + g * 32, 1u);
        if (old == s * GSZ - 1) {
            unsigned ro = atomicAdd(bar, 1u);
            if (ro == s * NGRP - 1)
                __hip_atomic_store(bar + 32, s, __ATOMIC_RELAXED,
                                   __HIP_MEMORY_SCOPE_AGENT);
        }
    }
}
__device__ __forceinline__ void gbar_wait(unsigned* bar, unsigned s)
{
    if (threadIdx.x == 0) {
        while (__hip_atomic_load(bar + 32, __ATOMIC_RELAXED,
                                 __HIP_MEMORY_SCOPE_AGENT) < s)
            __builtin_amdgcn_s_sleep(1);
    }
    __syncthreads();
}

// ---- ABLATION: pure barrier cost, 256 iterations, separate counter block ----
__global__ void __launch_bounds__(256) abl_bar(char* __restrict__ ws, int iters)
{
    unsigned* bar = (unsigned*)(ws + OFF_BAR) + 512;
    unsigned s = 0;
    for (int i = 0; i < iters; ++i) {
        ++s;
        gbar_arrive(bar, blockIdx.x, s);
        gbar_wait(bar, s);
    }
}

// Persistent wavefront-skewed 3-layer LSTM. 96 wgs x 256 thr, 64KB dyn LDS.
// wg = layer*32 + ug; each wg owns 16 units (all 4 gates), all 128 batches.
// NEW: all 32 A-fragments of a mat are staged into registers up front so the
// coherent loads issue back-to-back (~32 outstanding vs ~4).
__global__ void __launch_bounds__(256)
lstm_main(char* __restrict__ ws, const float* __restrict__ W2,
          const float* __restrict__ b2, float* __restrict__ out)
{
    extern __shared__ char ldsraw[];
    unsigned short* w_lds = (unsigned short*)ldsraw;       // 32768 u16 = 64KB
    __shared__ __align__(16) unsigned short stage[4][2][16][16];  // 4KB transpose stage

    const int tid  = threadIdx.x;
    const int lane = tid & 63;
    const int wv   = tid >> 6;
    const int q    = lane >> 4;
    const int l15  = lane & 15;
    const int wg   = blockIdx.x;
    const int layer = wg >> 5;
    const int ug    = wg & 31;

    unsigned short* hr = (unsigned short*)(ws + OFF_HR);
    float* part3 = (float*)(ws + OFF_P3);
    const float* xT = (const float*)(ws + OFF_XT);
    unsigned* bar = (unsigned*)(ws + OFF_BAR);

    // park Whh B-fragments in LDS (64KB once; plain cached loads, read-only)
    {
        const unsigned short* src = (const unsigned short*)
            (ws + ((layer == 0) ? OFF_WH1 : (layer == 1) ? OFF_WH2 : OFF_WH3))
            + (size_t)ug * 32768;
        for (int i = tid * 8; i < 32768; i += 256 * 8)
            *(short8*)(w_lds + i) = *(const short8*)(src + i);
    }
    // per-lane constants: unit gu = ug*16 + l15, gate g
    float cv[4], cu_[4];
    {
        int gu = ug * 16 + l15;
        if (layer == 0) {
            const float* v1 = (const float*)(ws + OFF_V1);
            const float* u1 = (const float*)(ws + OFF_U1);
            #pragma unroll
            for (int g = 0; g < 4; ++g) { cv[g] = v1[g * 512 + gu]; cu_[g] = u1[g * 512 + gu]; }
        } else {
            const float* bs = (const float*)(ws + ((layer == 1) ? OFF_B2 : OFF_B3));
            #pragma unroll
            for (int g = 0; g < 4; ++g) { cv[g] = bs[g * 512 + gu]; cu_[g] = 0.f; }
        }
    }
    const float w2v = (layer == 2) ? W2[ug * 16 + l15] : 0.f;
    const float b2v = b2[0];
    const unsigned short* wi_g = (const unsigned short*)
        (ws + ((layer == 1) ? OFF_WI2 : OFF_WI3)) + (size_t)ug * 32768;

    float c_st[2][4] = {};          // cell state [m][rr], register-resident
    __syncthreads();                // w_lds parked

    unsigned bstep = 0;
    for (int w = 0; w < NSTEP; ++w) {
        const int cur = w & 1, prev = cur ^ 1;
        const int t = w - layer;
        if (t >= 0 && t < 512) {
            f32x4 acc[2][4] = {};
            short8 A[32];
            // mat 0 (layers 1,2): stage ALL 32 A-frags, then consume
            if (layer != 0) {
                const u64* hA = (const u64*)(hr + (size_t)((layer - 1) * 2 + prev) * 65536);
                #pragma unroll
                for (int kb = 0; kb < 16; ++kb) {
                    A[2 * kb]     = cload(hA + (kb * 8 + 2 * wv    ) * 128 + lane * 2);
                    A[2 * kb + 1] = cload(hA + (kb * 8 + 2 * wv + 1) * 128 + lane * 2);
                }
                #pragma unroll
                for (int kb = 0; kb < 16; ++kb) {
                    #pragma unroll
                    for (int nb = 0; nb < 4; ++nb) {
                        short8 bw = *(const short8*)(wi_g + ((nb * 16 + kb) * 512) + lane * 8);
                        acc[0][nb] = __builtin_amdgcn_mfma_f32_16x16x32_bf16(A[2 * kb],     bw, acc[0][nb], 0, 0, 0);
                        acc[1][nb] = __builtin_amdgcn_mfma_f32_16x16x32_bf16(A[2 * kb + 1], bw, acc[1][nb], 0, 0, 0);
                    }
                }
            }
            // mat 1: Whh @ h_self(t-1): stage, then consume from LDS weights
            {
                const u64* hS = (const u64*)(hr + (size_t)(layer * 2 + prev) * 65536);
                #pragma unroll
                for (int kb = 0; kb < 16; ++kb) {
                    A[2 * kb]     = cload(hS + (kb * 8 + 2 * wv    ) * 128 + lane * 2);
                    A[2 * kb + 1] = cload(hS + (kb * 8 + 2 * wv + 1) * 128 + lane * 2);
                }
                #pragma unroll
                for (int kb = 0; kb < 16; ++kb) {
                    #pragma unroll
                    for (int nb = 0; nb < 4; ++nb) {
                        short8 bw = *(const short8*)(w_lds + ((nb * 16 + kb) * 512) + lane * 8);
                        acc[0][nb] = __builtin_amdgcn_mfma_f32_16x16x32_bf16(A[2 * kb],     bw, acc[0][nb], 0, 0, 0);
                        acc[1][nb] = __builtin_amdgcn_mfma_f32_16x16x32_bf16(A[2 * kb + 1], bw, acc[1][nb], 0, 0, 0);
                    }
                }
            }
            // epilogue: gates in-lane; h -> LDS transpose stage (+ part3 partials)
            #pragma unroll
            for (int m = 0; m < 2; ++m) {
                const int mblk = 2 * wv + m;
                #pragma unroll
                for (int rr = 0; rr < 4; ++rr) {
                    const int b = mblk * 16 + q * 4 + rr;
                    const float xv = (layer == 0) ? xT[t * 128 + b] : 1.0f;
                    float gi = acc[m][0][rr] + xv * cv[0] + cu_[0];
                    float gf = acc[m][1][rr] + xv * cv[1] + cu_[1];
                    float gg = acc[m][2][rr] + xv * cv[2] + cu_[2];
                    float go = acc[m][3][rr] + xv * cv[3] + cu_[3];
                    float c = sigm(gf) * c_st[m][rr] + sigm(gi) * tanhf(gg);
                    c_st[m][rr] = c;
                    float h = sigm(go) * tanhf(c);
                    stage[wv][m][q * 4 + rr][l15] = bf16rne(h);
                    if (layer == 2) {
                        float v = h * w2v;                  // partial of out[b][t]
                        v += __shfl_xor(v, 1); v += __shfl_xor(v, 2);
                        v += __shfl_xor(v, 4); v += __shfl_xor(v, 8);
                        if (l15 == 0)
                            __hip_atomic_store(&part3[((size_t)(w % 3) * 32 + ug) * 128 + b],
                                               v, __ATOMIC_RELAXED, __HIP_MEMORY_SCOPE_AGENT);
                    }
                }
            }
            // publish h: per-lane u64 chunks (write-through, agent-coherent)
            #pragma unroll
            for (int m = 0; m < 2; ++m) {
                const int mblk = 2 * wv + m;
                u64* dst64 = (u64*)(hr + (size_t)(layer * 2 + cur) * 65536
                                       + ((size_t)(ug >> 1) * 8 + mblk) * 512);
                const int row = lane >> 2, q4 = lane & 3;
                u64 v = *(const u64*)&stage[wv][m][row][q4 * 4];
                const int idx = (((ug & 1) * 2 + (q4 >> 1)) * 16 + row) * 2 + (q4 & 1);
                __hip_atomic_store(dst64 + idx, v, __ATOMIC_RELAXED,
                                   __HIP_MEMORY_SCOPE_AGENT);
            }
        }
        // ---- barrier arrive ----
        gbar_arrive(bar, wg, ++bstep);
        // ---- overlapped: final output for t = w-3 (partials sealed at w-1) ----
        if (layer == 2 && w >= 3) {
            const int b = (wg - 64) * 4 + wv;              // 32 wgs x 4 waves = 128
            float v = 0.f;
            if (lane < 32)
                v = __hip_atomic_load(&part3[((size_t)((w - 1) % 3) * 32 + lane) * 128 + b],
                                      __ATOMIC_RELAXED, __HIP_MEMORY_SCOPE_AGENT);
            v += __shfl_xor(v, 1); v += __shfl_xor(v, 2); v += __shfl_xor(v, 4);
            v += __shfl_xor(v, 8); v += __shfl_xor(v, 16);
            if (lane == 0) out[(size_t)b * 512 + (w - 3)] = v + b2v;
        }
        // ---- barrier wait ----
        gbar_wait(bar, bstep);
    }
}

// Kept to match the harness-provided template symbol (unused).
__global__ void Sequence_85564338471528_kernel() {}

extern "C" void kernel_launch(void* const* d_in, const int* in_sizes, int n_in,
                              void* d_out, int out_size, void* d_ws, size_t ws_size,
                              hipStream_t stream)
{
    const float* x    = (const float*)d_in[0];
    const float* W1   = (const float*)d_in[2];
    const float* b1   = (const float*)d_in[3];
    const float* W2   = (const float*)d_in[4];
    const float* b2   = (const float*)d_in[5];
    const float* Wih1 = (const float*)d_in[6];
    const float* Whh1 = (const float*)d_in[7];
    const float* bih1 = (const float*)d_in[8];
    const float* bhh1 = (const float*)d_in[9];
    const float* Wih2 = (const float*)d_in[10];
    const float* Whh2 = (const float*)d_in[11];
    const float* bih2 = (const float*)d_in[12];
    const float* bhh2 = (const float*)d_in[13];
    const float* Wih3 = (const float*)d_in[14];
    const float* Whh3 = (const float*)d_in[15];
    const float* bih3 = (const float*)d_in[16];
    const float* bhh3 = (const float*)d_in[17];
    char* ws = (char*)d_ws;
    float* out = (float*)d_out;

    fill_sentinel<<<256, 256, 0, stream>>>(out);
    zero_bar<<<1, 1024, 0, stream>>>(ws);
    zero_hr<<<204, 256, 0, stream>>>(ws);

    pack_w<<<4096, 256, 0, stream>>>(Whh1, (unsigned short*)(ws + OFF_WH1));
    pack_w<<<4096, 256, 0, stream>>>(Whh2, (unsigned short*)(ws + OFF_WH2));
    pack_w<<<4096, 256, 0, stream>>>(Whh3, (unsigned short*)(ws + OFF_WH3));
    pack_w<<<4096, 256, 0, stream>>>(Wih2, (unsigned short*)(ws + OFF_WI2));
    pack_w<<<4096, 256, 0, stream>>>(Wih3, (unsigned short*)(ws + OFF_WI3));
    prep_vec<<<8, 256, 0, stream>>>(Wih1, W1, b1, bih1, bhh1, bih2, bhh2, bih3, bhh3,
                                    (float*)(ws + OFF_V1), (float*)(ws + OFF_U1),
                                    (float*)(ws + OFF_B2), (float*)(ws + OFF_B3));
    prep_xt<<<256, 256, 0, stream>>>(x, (float*)(ws + OFF_XT));

    lstm_main<<<dim3(NWG), dim3(256), 65536, stream>>>(ws, W2, b2, out);
    // ablation: pure-barrier cost probe (256 iters), separate counter block
    abl_bar<<<dim3(NWG), dim3(256), 0, stream>>>(ws, 256);
}

// Round 12
// 9706.157 us; speedup vs baseline: 1.1304x; 1.1304x over previous
//
#include <hip/hip_runtime.h>

typedef short short8 __attribute__((ext_vector_type(8)));
typedef float f32x4  __attribute__((ext_vector_type(4)));
typedef unsigned long long u64;

#define NWG 96           // 32 wgs per layer, 16 units each
#define NSTEP 515
#define NGRP 8           // barrier groups
#define GSZ  12          // arrivers per group (96/8)

// ---- workspace layout (bytes) ----
#define OFF_WH1  0ull              // packed Whh1 frags: 32 ug * 64KB = 2MB
#define OFF_WH2  2097152ull        // packed Whh2
#define OFF_WH3  4194304ull        // packed Whh3
#define OFF_WI2  6291456ull        // packed Wih2 (streamed, L2-resident)
#define OFF_WI3  8388608ull        // packed Wih3
#define OFF_V1   10485760ull       // v1[2048] f32 (Wih1 @ W1)
#define OFF_U1   10493952ull       // u1[2048] f32 (Wih1 @ b1 + bih1 + bhh1)
#define OFF_B2   10502144ull       // bias2[2048] f32
#define OFF_B3   10510336ull       // bias3[2048] f32
#define OFF_XT   10518528ull       // xT[512][128] f32 (256KB)
#define OFF_HR   10780672ull       // h rings: [3 layer][2 slot][16 kb][8 mb][512] u16 = 768KB
#define OFF_P3   11567104ull       // part3: [3 slot][32][128] f32 = 48KB (3-ring)
#define OFF_BAR  11616256ull       // barrier block (4KB)

__device__ __forceinline__ unsigned short bf16rne(float f) {
    unsigned u = __float_as_uint(f);
    return (unsigned short)((u + 0x7FFFu + ((u >> 16) & 1u)) >> 16);
}

__device__ __forceinline__ float sigm(float x) { return 1.0f / (1.0f + expf(-x)); }

// Coherent 16B load: plain global_load_dwordx4 with sc0 sc1 (bypass L1/L2,
// served at the coherence point) — NO legalizer-inserted per-load waitcnt.
// Caller batches loads, then waits once via vm_drain().
__device__ __forceinline__ short8 cload16(const void* p) {
    short8 r;
    asm volatile("global_load_dwordx4 %0, %1, off sc0 sc1" : "=v"(r) : "v"(p));
    return r;
}
__device__ __forceinline__ void vm_drain() {
    asm volatile("s_waitcnt vmcnt(0)" ::: "memory");
    __builtin_amdgcn_sched_barrier(0);       // rule #18: keep MFMAs below the wait
}

// Sentinel: 0.0508 absmax -> nothing ran (e.g. asm didn't assemble);
// ~0.75 -> lstm_main broken; ~2e-4 -> PASS.
__global__ void fill_sentinel(float* __restrict__ out)
{
    int e = blockIdx.x * 256 + threadIdx.x;
    if (e < 65536) out[e] = 0.75f;
}

__global__ void zero_bar(char* __restrict__ ws)
{
    ((unsigned*)(ws + OFF_BAR))[threadIdx.x] = 0u;   // 1024 thr clear 4KB
}

// Zero h rings + part3 in a PRE-kernel (kernel-boundary flush publishes zeros).
__global__ void zero_hr(char* __restrict__ ws)
{
    int e = blockIdx.x * 256 + threadIdx.x;
    float4 z = {0.f, 0.f, 0.f, 0.f};
    if (e < 52224) *(float4*)(ws + OFF_HR + (size_t)e * 16) = z;  // HR(768K)+P3(48K)
}

// Pack one 2048x512 gate matrix into MFMA B-fragments (bf16 bits).
__global__ void pack_w(const float* __restrict__ W, unsigned short* __restrict__ dst)
{
    int e = blockIdx.x * 256 + threadIdx.x;     // exactly 1,048,576
    int j    = e & 7;
    int lane = (e >> 3) & 63;
    int kb   = (e >> 9) & 15;
    int nb   = (e >> 13) & 3;
    int ug   = e >> 15;
    int row = nb * 512 + ug * 16 + (lane & 15);
    int col = kb * 32 + (lane >> 4) * 8 + j;
    dst[e] = bf16rne(W[row * 512 + col]);
}

// v1 = Wih1 @ W1[:,0]; u1 = Wih1 @ b1 + bih1 + bhh1; bias2/3 = bih+bhh
__global__ void prep_vec(const float* __restrict__ Wih1, const float* __restrict__ W1,
                         const float* __restrict__ b1,
                         const float* __restrict__ bih1, const float* __restrict__ bhh1,
                         const float* __restrict__ bih2, const float* __restrict__ bhh2,
                         const float* __restrict__ bih3, const float* __restrict__ bhh3,
                         float* __restrict__ v1, float* __restrict__ u1,
                         float* __restrict__ bias2, float* __restrict__ bias3)
{
    int r = blockIdx.x * 256 + threadIdx.x;
    if (r >= 2048) return;
    float sv = 0.f, su = 0.f;
    for (int k = 0; k < 512; ++k) {
        float w = Wih1[r * 512 + k];
        sv += w * W1[k];
        su += w * b1[k];
    }
    v1[r] = sv;
    u1[r] = su + bih1[r] + bhh1[r];
    bias2[r] = bih2[r] + bhh2[r];
    bias3[r] = bih3[r] + bhh3[r];
}

__global__ void prep_xt(const float* __restrict__ x, float* __restrict__ xT)
{
    int e = blockIdx.x * 256 + threadIdx.x;
    if (e >= 65536) return;
    int b = e >> 9, t = e & 511;
    xT[t * 128 + b] = x[e];
}

// ---- fence-free hierarchical split-phase barrier (measured: ~1.7us/step) ----
__device__ __forceinline__ void gbar_arrive(unsigned* bar, int wg, unsigned s)
{
    __syncthreads();                      // drains vmcnt: h stores at coherence pt
    if (threadIdx.x == 0) {
        unsigned g = (unsigned)wg & 7u;
        unsigned old = atomicAdd(bar + 64 + g * 32, 1u);
        if (old == s * GSZ - 1) {
            unsigned ro = atomicAdd(bar, 1u);
            if (ro == s * NGRP - 1)
                __hip_atomic_store(bar + 32, s, __ATOMIC_RELAXED,
                                   __HIP_MEMORY_SCOPE_AGENT);
        }
    }
}
__device__ __forceinline__ void gbar_wait(unsigned* bar, unsigned s)
{
    if (threadIdx.x == 0) {
        while (__hip_atomic_load(bar + 32, __ATOMIC_RELAXED,
                                 __HIP_MEMORY_SCOPE_AGENT) < s)
            __builtin_amdgcn_s_sleep(1);
    }
    __syncthreads();
}

// Persistent wavefront-skewed 3-layer LSTM. 96 wgs x 256 thr, 64KB dyn LDS.
// wg = layer*32 + ug; each wg owns 16 units (all 4 gates), all 128 batches.
// h loads: batched raw sc0sc1 loads + ONE vmcnt drain per mat (vs per-load).
__global__ void __launch_bounds__(256)
lstm_main(char* __restrict__ ws, const float* __restrict__ W2,
          const float* __restrict__ b2, float* __restrict__ out)
{
    extern __shared__ char ldsraw[];
    unsigned short* w_lds = (unsigned short*)ldsraw;       // 32768 u16 = 64KB
    __shared__ __align__(16) unsigned short stage[4][2][16][16];  // 4KB transpose stage

    const int tid  = threadIdx.x;
    const int lane = tid & 63;
    const int wv   = tid >> 6;
    const int q    = lane >> 4;
    const int l15  = lane & 15;
    const int wg   = blockIdx.x;
    const int layer = wg >> 5;
    const int ug    = wg & 31;

    unsigned short* hr = (unsigned short*)(ws + OFF_HR);
    float* part3 = (float*)(ws + OFF_P3);
    const float* xT = (const float*)(ws + OFF_XT);
    unsigned* bar = (unsigned*)(ws + OFF_BAR);

    // park Whh B-fragments in LDS (64KB once; plain cached loads, read-only)
    {
        const unsigned short* src = (const unsigned short*)
            (ws + ((layer == 0) ? OFF_WH1 : (layer == 1) ? OFF_WH2 : OFF_WH3))
            + (size_t)ug * 32768;
        for (int i = tid * 8; i < 32768; i += 256 * 8)
            *(short8*)(w_lds + i) = *(const short8*)(src + i);
    }
    // per-lane constants: unit gu = ug*16 + l15, gate g
    float cv[4], cu_[4];
    {
        int gu = ug * 16 + l15;
        if (layer == 0) {
            const float* v1 = (const float*)(ws + OFF_V1);
            const float* u1 = (const float*)(ws + OFF_U1);
            #pragma unroll
            for (int g = 0; g < 4; ++g) { cv[g] = v1[g * 512 + gu]; cu_[g] = u1[g * 512 + gu]; }
        } else {
            const float* bs = (const float*)(ws + ((layer == 1) ? OFF_B2 : OFF_B3));
            #pragma unroll
            for (int g = 0; g < 4; ++g) { cv[g] = bs[g * 512 + gu]; cu_[g] = 0.f; }
        }
    }
    const float w2v = (layer == 2) ? W2[ug * 16 + l15] : 0.f;
    const float b2v = b2[0];
    const unsigned short* wi_g = (const unsigned short*)
        (ws + ((layer == 1) ? OFF_WI2 : OFF_WI3)) + (size_t)ug * 32768;

    float c_st[2][4] = {};          // cell state [m][rr], register-resident
    __syncthreads();                // w_lds parked

    unsigned bstep = 0;
    for (int w = 0; w < NSTEP; ++w) {
        const int cur = w & 1, prev = cur ^ 1;
        const int t = w - layer;
        if (t >= 0 && t < 512) {
            f32x4 acc[2][4] = {};
            short8 A[32];
            // mat 0 (layers 1,2): batch-load 32 A-frags, drain once, consume
            if (layer != 0) {
                const unsigned short* hA = hr + (size_t)((layer - 1) * 2 + prev) * 65536;
                #pragma unroll
                for (int kb = 0; kb < 16; ++kb) {
                    A[2 * kb]     = cload16(hA + (kb * 8 + 2 * wv    ) * 512 + lane * 8);
                    A[2 * kb + 1] = cload16(hA + (kb * 8 + 2 * wv + 1) * 512 + lane * 8);
                }
                vm_drain();
                #pragma unroll
                for (int kb = 0; kb < 16; ++kb) {
                    #pragma unroll
                    for (int nb = 0; nb < 4; ++nb) {
                        short8 bw = *(const short8*)(wi_g + ((nb * 16 + kb) * 512) + lane * 8);
                        acc[0][nb] = __builtin_amdgcn_mfma_f32_16x16x32_bf16(A[2 * kb],     bw, acc[0][nb], 0, 0, 0);
                        acc[1][nb] = __builtin_amdgcn_mfma_f32_16x16x32_bf16(A[2 * kb + 1], bw, acc[1][nb], 0, 0, 0);
                    }
                }
            }
            // mat 1: batch-load 32 A-frags (h_self), drain once, consume from LDS
            {
                const unsigned short* hS = hr + (size_t)(layer * 2 + prev) * 65536;
                #pragma unroll
                for (int kb = 0; kb < 16; ++kb) {
                    A[2 * kb]     = cload16(hS + (kb * 8 + 2 * wv    ) * 512 + lane * 8);
                    A[2 * kb + 1] = cload16(hS + (kb * 8 + 2 * wv + 1) * 512 + lane * 8);
                }
                vm_drain();
                #pragma unroll
                for (int kb = 0; kb < 16; ++kb) {
                    #pragma unroll
                    for (int nb = 0; nb < 4; ++nb) {
                        short8 bw = *(const short8*)(w_lds + ((nb * 16 + kb) * 512) + lane * 8);
                        acc[0][nb] = __builtin_amdgcn_mfma_f32_16x16x32_bf16(A[2 * kb],     bw, acc[0][nb], 0, 0, 0);
                        acc[1][nb] = __builtin_amdgcn_mfma_f32_16x16x32_bf16(A[2 * kb + 1], bw, acc[1][nb], 0, 0, 0);
                    }
                }
            }
            // epilogue: gates in-lane; h -> LDS transpose stage (+ part3 partials)
            #pragma unroll
            for (int m = 0; m < 2; ++m) {
                const int mblk = 2 * wv + m;
                #pragma unroll
                for (int rr = 0; rr < 4; ++rr) {
                    const int b = mblk * 16 + q * 4 + rr;
                    const float xv = (layer == 0) ? xT[t * 128 + b] : 1.0f;
                    float gi = acc[m][0][rr] + xv * cv[0] + cu_[0];
                    float gf = acc[m][1][rr] + xv * cv[1] + cu_[1];
                    float gg = acc[m][2][rr] + xv * cv[2] + cu_[2];
                    float go = acc[m][3][rr] + xv * cv[3] + cu_[3];
                    float c = sigm(gf) * c_st[m][rr] + sigm(gi) * tanhf(gg);
                    c_st[m][rr] = c;
                    float h = sigm(go) * tanhf(c);
                    stage[wv][m][q * 4 + rr][l15] = bf16rne(h);
                    if (layer == 2) {
                        float v = h * w2v;                  // partial of out[b][t]
                        v += __shfl_xor(v, 1); v += __shfl_xor(v, 2);
                        v += __shfl_xor(v, 4); v += __shfl_xor(v, 8);
                        if (l15 == 0)
                            __hip_atomic_store(&part3[((size_t)(w % 3) * 32 + ug) * 128 + b],
                                               v, __ATOMIC_RELAXED, __HIP_MEMORY_SCOPE_AGENT);
                    }
                }
            }
            // publish h: per-lane u64 chunks (write-through, agent-coherent)
            #pragma unroll
            for (int m = 0; m < 2; ++m) {
                const int mblk = 2 * wv + m;
                u64* dst64 = (u64*)(hr + (size_t)(layer * 2 + cur) * 65536
                                       + ((size_t)(ug >> 1) * 8 + mblk) * 512);
                const int row = lane >> 2, q4 = lane & 3;
                u64 v = *(const u64*)&stage[wv][m][row][q4 * 4];
                const int idx = (((ug & 1) * 2 + (q4 >> 1)) * 16 + row) * 2 + (q4 & 1);
                __hip_atomic_store(dst64 + idx, v, __ATOMIC_RELAXED,
                                   __HIP_MEMORY_SCOPE_AGENT);
            }
        }
        // ---- barrier arrive ----
        gbar_arrive(bar, wg, ++bstep);
        // ---- overlapped: final output for t = w-3 (partials sealed at w-1) ----
        if (layer == 2 && w >= 3) {
            const int b = (wg - 64) * 4 + wv;              // 32 wgs x 4 waves = 128
            float v = 0.f;
            if (lane < 32)
                v = __hip_atomic_load(&part3[((size_t)((w - 1) % 3) * 32 + lane) * 128 + b],
                                      __ATOMIC_RELAXED, __HIP_MEMORY_SCOPE_AGENT);
            v += __shfl_xor(v, 1); v += __shfl_xor(v, 2); v += __shfl_xor(v, 4);
            v += __shfl_xor(v, 8); v += __shfl_xor(v, 16);
            if (lane == 0) out[(size_t)b * 512 + (w - 3)] = v + b2v;
        }
        // ---- barrier wait ----
        gbar_wait(bar, bstep);
    }
}

// Kept to match the harness-provided template symbol (unused).
__global__ void Sequence_85564338471528_kernel() {}

extern "C" void kernel_launch(void* const* d_in, const int* in_sizes, int n_in,
                              void* d_out, int out_size, void* d_ws, size_t ws_size,
                              hipStream_t stream)
{
    const float* x    = (const float*)d_in[0];
    const float* W1   = (const float*)d_in[2];
    const float* b1   = (const float*)d_in[3];
    const float* W2   = (const float*)d_in[4];
    const float* b2   = (const float*)d_in[5];
    const float* Wih1 = (const float*)d_in[6];
    const float* Whh1 = (const float*)d_in[7];
    const float* bih1 = (const float*)d_in[8];
    const float* bhh1 = (const float*)d_in[9];
    const float* Wih2 = (const float*)d_in[10];
    const float* Whh2 = (const float*)d_in[11];
    const float* bih2 = (const float*)d_in[12];
    const float* bhh2 = (const float*)d_in[13];
    const float* Wih3 = (const float*)d_in[14];
    const float* Whh3 = (const float*)d_in[15];
    const float* bih3 = (const float*)d_in[16];
    const float* bhh3 = (const float*)d_in[17];
    char* ws = (char*)d_ws;
    float* out = (float*)d_out;

    fill_sentinel<<<256, 256, 0, stream>>>(out);
    zero_bar<<<1, 1024, 0, stream>>>(ws);
    zero_hr<<<204, 256, 0, stream>>>(ws);

    pack_w<<<4096, 256, 0, stream>>>(Whh1, (unsigned short*)(ws + OFF_WH1));
    pack_w<<<4096, 256, 0, stream>>>(Whh2, (unsigned short*)(ws + OFF_WH2));
    pack_w<<<4096, 256, 0, stream>>>(Whh3, (unsigned short*)(ws + OFF_WH3));
    pack_w<<<4096, 256, 0, stream>>>(Wih2, (unsigned short*)(ws + OFF_WI2));
    pack_w<<<4096, 256, 0, stream>>>(Wih3, (unsigned short*)(ws + OFF_WI3));
    prep_vec<<<8, 256, 0, stream>>>(Wih1, W1, b1, bih1, bhh1, bih2, bhh2, bih3, bhh3,
                                    (float*)(ws + OFF_V1), (float*)(ws + OFF_U1),
                                    (float*)(ws + OFF_B2), (float*)(ws + OFF_B3));
    prep_xt<<<256, 256, 0, stream>>>(x, (float*)(ws + OFF_XT));

    lstm_main<<<dim3(NWG), dim3(256), 65536, stream>>>(ws, W2, b2, out);
}